// Round 1
// baseline (3351.478 us; speedup 1.0000x reference)
//
#include <hip/hip_runtime.h>
#include <hip/hip_bf16.h>

// TextDecoder: 2-layer LSTM, B=64, H=1024, V=10000, T=32 steps (31 computed).
// Round 0: pure fp32, deterministic K-split GEMMs + fused cell updates.
// ws layout (floats): h1[64K] c1[64K] h2[64K] c2[64K] part[8*256K] amax[64 ints]
// total ~9.4 MB.

#define HDIM 1024
#define BDIM 64
#define VDIM 10000
#define TDIM 32

__device__ __forceinline__ float sigmoidf_(float x) {
    return 1.0f / (1.0f + expf(-x));
}

// C_partial[slab] = A[64 x klen] * W[N x 1024]^T restricted to k-range.
// A row-major ld=1024, W row-major ld=1024. Tile 64x64, K-split over blockIdx.y,
// matrix select over blockIdx.z (for layer-1's two input GEMMs).
__global__ __launch_bounds__(256) void gemm_ksplit(
    const float* __restrict__ A0, const float* __restrict__ W0,
    const float* __restrict__ A1, const float* __restrict__ W1,
    float* __restrict__ part, int N, int KS)
{
    const int tid = threadIdx.x;
    const int nblk = blockIdx.x;
    const int q = blockIdx.y;
    const int z = blockIdx.z;
    const float* __restrict__ A = z ? A1 : A0;
    const float* __restrict__ W = z ? W1 : W0;
    const int klen = HDIM / KS;
    const int kbase = q * klen;
    const int n0 = nblk * 64;
    const int slab = z * KS + q;

    __shared__ float As[32][64];
    __shared__ float Ws[32][64];

    float acc[4][4] = {};
    const int ty = tid >> 4, tx = tid & 15;
    const int b0 = ty * 4, c0 = tx * 4;

    const int ldr = tid >> 2;          // 0..63: row index for staging loads
    const int lk  = (tid & 3) * 8;     // 0,8,16,24: k offset for staging loads

    for (int kc = 0; kc < klen; kc += 32) {
        // Stage A chunk k-major: As[kk][b]
        {
            const float* src = A + ldr * HDIM + kbase + kc + lk;
            float4 v0 = *(const float4*)(src);
            float4 v1 = *(const float4*)(src + 4);
            As[lk+0][ldr] = v0.x; As[lk+1][ldr] = v0.y;
            As[lk+2][ldr] = v0.z; As[lk+3][ldr] = v0.w;
            As[lk+4][ldr] = v1.x; As[lk+5][ldr] = v1.y;
            As[lk+6][ldr] = v1.z; As[lk+7][ldr] = v1.w;
        }
        // Stage W chunk k-major: Ws[kk][n]
        {
            int n = n0 + ldr;
            if (n < N) {
                const float* src = W + (size_t)n * HDIM + kbase + kc + lk;
                float4 v0 = *(const float4*)(src);
                float4 v1 = *(const float4*)(src + 4);
                Ws[lk+0][ldr] = v0.x; Ws[lk+1][ldr] = v0.y;
                Ws[lk+2][ldr] = v0.z; Ws[lk+3][ldr] = v0.w;
                Ws[lk+4][ldr] = v1.x; Ws[lk+5][ldr] = v1.y;
                Ws[lk+6][ldr] = v1.z; Ws[lk+7][ldr] = v1.w;
            } else {
                #pragma unroll
                for (int i = 0; i < 8; i++) Ws[lk+i][ldr] = 0.0f;
            }
        }
        __syncthreads();
        #pragma unroll
        for (int kk = 0; kk < 32; kk++) {
            float4 a = *(const float4*)&As[kk][b0];
            float4 w = *(const float4*)&Ws[kk][c0];
            acc[0][0] += a.x*w.x; acc[0][1] += a.x*w.y; acc[0][2] += a.x*w.z; acc[0][3] += a.x*w.w;
            acc[1][0] += a.y*w.x; acc[1][1] += a.y*w.y; acc[1][2] += a.y*w.z; acc[1][3] += a.y*w.w;
            acc[2][0] += a.z*w.x; acc[2][1] += a.z*w.y; acc[2][2] += a.z*w.z; acc[2][3] += a.z*w.w;
            acc[3][0] += a.w*w.x; acc[3][1] += a.w*w.y; acc[3][2] += a.w*w.z; acc[3][3] += a.w*w.w;
        }
        __syncthreads();
    }

    float* dst = part + (size_t)slab * 64 * N;
    if (n0 + 64 <= N) {
        #pragma unroll
        for (int i = 0; i < 4; i++) {
            float4 v = make_float4(acc[i][0], acc[i][1], acc[i][2], acc[i][3]);
            *(float4*)&dst[(size_t)(b0 + i) * N + n0 + c0] = v;
        }
    } else {
        for (int i = 0; i < 4; i++)
            for (int j = 0; j < 4; j++) {
                int col = n0 + c0 + j;
                if (col < N) dst[(size_t)(b0 + i) * N + col] = acc[i][j];
            }
    }
}

// Layer-0 cell update: gates = sum(4 partials) + b_ih + b_hh + Wih0[:, tok]
__global__ __launch_bounds__(256) void cell0_kernel(
    const float* __restrict__ part,
    const float* __restrict__ Wih0, const float* __restrict__ bih,
    const float* __restrict__ bhh,
    const int* __restrict__ captions, const int* __restrict__ tfmask,
    const int* __restrict__ amax,
    float* __restrict__ h1, float* __restrict__ c1, int t)
{
    int idx = blockIdx.x * 256 + threadIdx.x;   // 0..65535
    int b = idx >> 10, i = idx & 1023;
    int tok;
    if (t == 1) tok = captions[b * TDIM];
    else tok = tfmask[t - 1] ? captions[b * TDIM + (t - 1)] : amax[b];

    float g[4];
    #pragma unroll
    for (int gi = 0; gi < 4; gi++) {
        int j = gi * HDIM + i;
        float s = bih[j] + bhh[j] + Wih0[(size_t)j * VDIM + tok];
        #pragma unroll
        for (int q = 0; q < 4; q++) s += part[(size_t)q * 262144 + b * 4096 + j];
        g[gi] = s;
    }
    float ig = sigmoidf_(g[0]), fg = sigmoidf_(g[1]);
    float gg = tanhf(g[2]),     og = sigmoidf_(g[3]);
    float cn = fg * c1[idx] + ig * gg;
    float hn = og * tanhf(cn);
    c1[idx] = cn; h1[idx] = hn;
}

// Layer-1 cell update: gates = sum(8 partials) + b_ih + b_hh
__global__ __launch_bounds__(256) void cell1_kernel(
    const float* __restrict__ part,
    const float* __restrict__ bih, const float* __restrict__ bhh,
    float* __restrict__ h2, float* __restrict__ c2)
{
    int idx = blockIdx.x * 256 + threadIdx.x;
    int b = idx >> 10, i = idx & 1023;
    float g[4];
    #pragma unroll
    for (int gi = 0; gi < 4; gi++) {
        int j = gi * HDIM + i;
        float s = bih[j] + bhh[j];
        #pragma unroll
        for (int q = 0; q < 8; q++) s += part[(size_t)q * 262144 + b * 4096 + j];
        g[gi] = s;
    }
    float ig = sigmoidf_(g[0]), fg = sigmoidf_(g[1]);
    float gg = tanhf(g[2]),     og = sigmoidf_(g[3]);
    float cn = fg * c2[idx] + ig * gg;
    float hn = og * tanhf(cn);
    c2[idx] = cn; h2[idx] = hn;
}

// Sum logit partials + bias, write out[:, t, :], block-reduce argmax per batch.
// Encoding: monotone(float) in high 32 bits, ~v in low 32 -> max picks highest
// value, ties broken toward smallest index (numpy argmax semantics).
__global__ __launch_bounds__(256) void sumarg_kernel(
    const float* __restrict__ part, const float* __restrict__ b_out,
    float* __restrict__ out, int* __restrict__ amax, int t)
{
    int b = blockIdx.x;
    int tid = threadIdx.x;
    const float* p0 = part + (size_t)b * VDIM;
    const float* p1 = part + (size_t)64 * VDIM + (size_t)b * VDIM;
    float* orow = out + (size_t)b * TDIM * VDIM + (size_t)t * VDIM;

    unsigned long long best = 0ull;
    for (int v = tid; v < VDIM; v += 256) {
        float s = p0[v] + p1[v] + b_out[v];
        orow[v] = s;
        unsigned u = __float_as_uint(s);
        u = (u & 0x80000000u) ? ~u : (u | 0x80000000u);
        unsigned long long e = ((unsigned long long)u << 32) | (unsigned)(~v);
        if (e > best) best = e;
    }
    #pragma unroll
    for (int off = 32; off > 0; off >>= 1) {
        unsigned long long o = __shfl_down(best, off, 64);
        if (o > best) best = o;
    }
    __shared__ unsigned long long red[4];
    if ((tid & 63) == 0) red[tid >> 6] = best;
    __syncthreads();
    if (tid == 0) {
        best = red[0];
        if (red[1] > best) best = red[1];
        if (red[2] > best) best = red[2];
        if (red[3] > best) best = red[3];
        amax[b] = (int)(~(unsigned)(best & 0xffffffffull));
    }
}

// Copy initial states, write out[:,0,:] = one_hot(captions[:,0]).
__global__ __launch_bounds__(256) void init_kernel(
    const float* __restrict__ hidden, const float* __restrict__ cell,
    const int* __restrict__ captions,
    float* __restrict__ h1, float* __restrict__ c1,
    float* __restrict__ h2, float* __restrict__ c2,
    float* __restrict__ out)
{
    int idx = blockIdx.x * 256 + threadIdx.x;
    if (idx < BDIM * HDIM) {
        h1[idx] = hidden[idx];
        h2[idx] = hidden[BDIM * HDIM + idx];
        c1[idx] = cell[idx];
        c2[idx] = cell[BDIM * HDIM + idx];
    }
    if (idx < BDIM * VDIM) {
        int b = idx / VDIM, v = idx % VDIM;
        out[(size_t)b * TDIM * VDIM + v] = (v == captions[b * TDIM]) ? 1.0f : 0.0f;
    }
}

extern "C" void kernel_launch(void* const* d_in, const int* in_sizes, int n_in,
                              void* d_out, int out_size, void* d_ws, size_t ws_size,
                              hipStream_t stream)
{
    const float* hidden = (const float*)d_in[0];
    const float* cellin = (const float*)d_in[1];
    const int*   captions = (const int*)d_in[2];
    const int*   tfmask = (const int*)d_in[3];
    const float* Wih0 = (const float*)d_in[4];
    const float* Whh0 = (const float*)d_in[5];
    const float* bih0 = (const float*)d_in[6];
    const float* bhh0 = (const float*)d_in[7];
    const float* Wih1 = (const float*)d_in[8];
    const float* Whh1 = (const float*)d_in[9];
    const float* bih1 = (const float*)d_in[10];
    const float* bhh1 = (const float*)d_in[11];
    const float* Wout = (const float*)d_in[12];
    const float* bout = (const float*)d_in[13];
    float* out = (float*)d_out;

    float* ws = (float*)d_ws;
    float* h1 = ws;
    float* c1 = ws + 65536;
    float* h2 = ws + 131072;
    float* c2 = ws + 196608;
    float* part = ws + 262144;                 // 8 slabs x 64x4096 (GEMM3 reuses)
    int*   amax = (int*)(ws + 262144 + 8 * 262144);

    init_kernel<<<2500, 256, 0, stream>>>(hidden, cellin, captions, h1, c1, h2, c2, out);

    for (int t = 1; t < TDIM; t++) {
        // Layer 0: gates partials = h1 @ Whh0^T (K split 4)
        gemm_ksplit<<<dim3(64, 4, 1), 256, 0, stream>>>(h1, Whh0, h1, Whh0, part, 4096, 4);
        cell0_kernel<<<256, 256, 0, stream>>>(part, Wih0, bih0, bhh0, captions, tfmask,
                                              amax, h1, c1, t);
        // Layer 1: partials = h1 @ Wih1^T (z=0) and h2 @ Whh1^T (z=1), 8 slabs
        gemm_ksplit<<<dim3(64, 4, 2), 256, 0, stream>>>(h1, Wih1, h2, Whh1, part, 4096, 4);
        cell1_kernel<<<256, 256, 0, stream>>>(part, bih1, bhh1, h2, c2);
        // Logits: partials = h2 @ Wout^T (K split 2), then sum+bias+argmax
        gemm_ksplit<<<dim3(157, 2, 1), 256, 0, stream>>>(h2, Wout, h2, Wout, part, 10000, 2);
        sumarg_kernel<<<64, 256, 0, stream>>>(part, bout, out, amax, t);
    }
}

// Round 2
// 3018.200 us; speedup vs baseline: 1.1104x; 1.1104x over previous
//
#include <hip/hip_runtime.h>
#include <hip/hip_bf16.h>

// TextDecoder: 2-layer LSTM, B=64, H=1024, V=10000, T=32 steps (31 computed).
// Round 1: split-fp16 MFMA GEMMs (x = hi + lo/2048, 3 MFMAs -> fp32-accurate),
// weights converted to fp16 hi/lo once per launch (L3-resident), fragments
// loaded directly from global (no LDS). Falls back to round-0 fp32 path if
// ws_size is too small for converted weights.

#define HDIM 1024
#define BDIM 64
#define VDIM 10000
#define VPAD 10048   // 157 * 64
#define TDIM 32

typedef _Float16 f16;
typedef _Float16 f16x8 __attribute__((ext_vector_type(8)));
typedef float f32x4 __attribute__((ext_vector_type(4)));

__device__ __forceinline__ float sigmoidf_(float x) {
    return 1.0f / (1.0f + expf(-x));
}

// ------------------------------------------------------------------
// Split-fp16 MFMA GEMM.  C_partial[slab] = A[64 x klen] * W[N x 1024]^T
// over k-range q. A,W given as fp16 hi/lo pairs (k-contiguous, ld=1024).
// Block tile 64x64 (2x2 waves of 32x32). Fragments straight from global.
// ------------------------------------------------------------------
__global__ __launch_bounds__(256) void gemm_mfma(
    const f16* __restrict__ Ah0, const f16* __restrict__ Al0,
    const f16* __restrict__ Wh0, const f16* __restrict__ Wl0,
    const f16* __restrict__ Ah1, const f16* __restrict__ Al1,
    const f16* __restrict__ Wh1, const f16* __restrict__ Wl1,
    float* __restrict__ part, int N, int KS)
{
    const int tid = threadIdx.x;
    const int wave = tid >> 6, lane = tid & 63;
    const int wr = wave >> 1, wc = wave & 1;
    const int q = blockIdx.y, z = blockIdx.z;
    const f16* __restrict__ Ah = z ? Ah1 : Ah0;
    const f16* __restrict__ Al = z ? Al1 : Al0;
    const f16* __restrict__ Wh = z ? Wh1 : Wh0;
    const f16* __restrict__ Wl = z ? Wl1 : Wl0;
    const int klen = HDIM / KS;
    const int kbase = q * klen;
    const int n0 = blockIdx.x * 64 + wc * 32;
    const int m0 = wr * 32;
    const int lm = lane & 15, quad = lane >> 4;
    const int slab = z * KS + q;

    f32x4 acc[2][2] = {};
    f32x4 accL[2][2] = {};

    const f16* a_h = Ah + (size_t)(m0 + lm) * HDIM + kbase + quad * 8;
    const f16* a_l = Al + (size_t)(m0 + lm) * HDIM + kbase + quad * 8;
    const f16* b_h = Wh + (size_t)(n0 + lm) * HDIM + kbase + quad * 8;
    const f16* b_l = Wl + (size_t)(n0 + lm) * HDIM + kbase + quad * 8;

    #pragma unroll 4
    for (int ko = 0; ko < klen; ko += 32) {
        f16x8 ah0 = *(const f16x8*)(a_h + ko);
        f16x8 ah1 = *(const f16x8*)(a_h + 16 * HDIM + ko);
        f16x8 al0 = *(const f16x8*)(a_l + ko);
        f16x8 al1 = *(const f16x8*)(a_l + 16 * HDIM + ko);
        f16x8 bh0 = *(const f16x8*)(b_h + ko);
        f16x8 bh1 = *(const f16x8*)(b_h + 16 * HDIM + ko);
        f16x8 bl0 = *(const f16x8*)(b_l + ko);
        f16x8 bl1 = *(const f16x8*)(b_l + 16 * HDIM + ko);

        acc[0][0] = __builtin_amdgcn_mfma_f32_16x16x32_f16(ah0, bh0, acc[0][0], 0, 0, 0);
        acc[0][1] = __builtin_amdgcn_mfma_f32_16x16x32_f16(ah0, bh1, acc[0][1], 0, 0, 0);
        acc[1][0] = __builtin_amdgcn_mfma_f32_16x16x32_f16(ah1, bh0, acc[1][0], 0, 0, 0);
        acc[1][1] = __builtin_amdgcn_mfma_f32_16x16x32_f16(ah1, bh1, acc[1][1], 0, 0, 0);

        accL[0][0] = __builtin_amdgcn_mfma_f32_16x16x32_f16(ah0, bl0, accL[0][0], 0, 0, 0);
        accL[0][1] = __builtin_amdgcn_mfma_f32_16x16x32_f16(ah0, bl1, accL[0][1], 0, 0, 0);
        accL[1][0] = __builtin_amdgcn_mfma_f32_16x16x32_f16(ah1, bl0, accL[1][0], 0, 0, 0);
        accL[1][1] = __builtin_amdgcn_mfma_f32_16x16x32_f16(ah1, bl1, accL[1][1], 0, 0, 0);

        accL[0][0] = __builtin_amdgcn_mfma_f32_16x16x32_f16(al0, bh0, accL[0][0], 0, 0, 0);
        accL[0][1] = __builtin_amdgcn_mfma_f32_16x16x32_f16(al0, bh1, accL[0][1], 0, 0, 0);
        accL[1][0] = __builtin_amdgcn_mfma_f32_16x16x32_f16(al1, bh0, accL[1][0], 0, 0, 0);
        accL[1][1] = __builtin_amdgcn_mfma_f32_16x16x32_f16(al1, bh1, accL[1][1], 0, 0, 0);
    }

    float* dst = part + (size_t)slab * 64 * N;
    #pragma unroll
    for (int rt = 0; rt < 2; rt++)
        #pragma unroll
        for (int ct = 0; ct < 2; ct++)
            #pragma unroll
            for (int r = 0; r < 4; r++) {
                int row = m0 + rt * 16 + quad * 4 + r;
                int col = n0 + ct * 16 + lm;
                dst[(size_t)row * N + col] =
                    acc[rt][ct][r] + accL[rt][ct][r] * (1.0f / 2048.0f);
            }
}

// Elementwise fp32 -> (hi fp16, lo fp16 scaled by 2048); zero-pads past n_src.
__global__ __launch_bounds__(256) void convert_split(
    const float* __restrict__ src, f16* __restrict__ hi, f16* __restrict__ lo,
    int n_src, int n_pad)
{
    int i = blockIdx.x * 256 + threadIdx.x;
    if (i >= n_pad) return;
    float x = (i < n_src) ? src[i] : 0.0f;
    f16 h = (f16)x;
    f16 l = (f16)((x - (float)h) * 2048.0f);
    hi[i] = h; lo[i] = l;
}

// ------------------------------------------------------------------
// Round-0 fp32 GEMM (fallback when ws too small for converted weights)
// ------------------------------------------------------------------
__global__ __launch_bounds__(256) void gemm_ksplit(
    const float* __restrict__ A0, const float* __restrict__ W0,
    const float* __restrict__ A1, const float* __restrict__ W1,
    float* __restrict__ part, int N, int KS)
{
    const int tid = threadIdx.x;
    const int nblk = blockIdx.x;
    const int q = blockIdx.y;
    const int z = blockIdx.z;
    const float* __restrict__ A = z ? A1 : A0;
    const float* __restrict__ W = z ? W1 : W0;
    const int klen = HDIM / KS;
    const int kbase = q * klen;
    const int n0 = nblk * 64;
    const int slab = z * KS + q;

    __shared__ float As[32][64];
    __shared__ float Ws[32][64];

    float acc[4][4] = {};
    const int ty = tid >> 4, tx = tid & 15;
    const int b0 = ty * 4, c0 = tx * 4;
    const int ldr = tid >> 2;
    const int lk  = (tid & 3) * 8;

    for (int kc = 0; kc < klen; kc += 32) {
        {
            const float* src = A + ldr * HDIM + kbase + kc + lk;
            float4 v0 = *(const float4*)(src);
            float4 v1 = *(const float4*)(src + 4);
            As[lk+0][ldr] = v0.x; As[lk+1][ldr] = v0.y;
            As[lk+2][ldr] = v0.z; As[lk+3][ldr] = v0.w;
            As[lk+4][ldr] = v1.x; As[lk+5][ldr] = v1.y;
            As[lk+6][ldr] = v1.z; As[lk+7][ldr] = v1.w;
        }
        {
            int n = n0 + ldr;
            if (n < N) {
                const float* src = W + (size_t)n * HDIM + kbase + kc + lk;
                float4 v0 = *(const float4*)(src);
                float4 v1 = *(const float4*)(src + 4);
                Ws[lk+0][ldr] = v0.x; Ws[lk+1][ldr] = v0.y;
                Ws[lk+2][ldr] = v0.z; Ws[lk+3][ldr] = v0.w;
                Ws[lk+4][ldr] = v1.x; Ws[lk+5][ldr] = v1.y;
                Ws[lk+6][ldr] = v1.z; Ws[lk+7][ldr] = v1.w;
            } else {
                #pragma unroll
                for (int i = 0; i < 8; i++) Ws[lk+i][ldr] = 0.0f;
            }
        }
        __syncthreads();
        #pragma unroll
        for (int kk = 0; kk < 32; kk++) {
            float4 a = *(const float4*)&As[kk][b0];
            float4 w = *(const float4*)&Ws[kk][c0];
            acc[0][0] += a.x*w.x; acc[0][1] += a.x*w.y; acc[0][2] += a.x*w.z; acc[0][3] += a.x*w.w;
            acc[1][0] += a.y*w.x; acc[1][1] += a.y*w.y; acc[1][2] += a.y*w.z; acc[1][3] += a.y*w.w;
            acc[2][0] += a.z*w.x; acc[2][1] += a.z*w.y; acc[2][2] += a.z*w.z; acc[2][3] += a.z*w.w;
            acc[3][0] += a.w*w.x; acc[3][1] += a.w*w.y; acc[3][2] += a.w*w.z; acc[3][3] += a.w*w.w;
        }
        __syncthreads();
    }

    float* dst = part + (size_t)slab * 64 * N;
    if (n0 + 64 <= N) {
        #pragma unroll
        for (int i = 0; i < 4; i++) {
            float4 v = make_float4(acc[i][0], acc[i][1], acc[i][2], acc[i][3]);
            *(float4*)&dst[(size_t)(b0 + i) * N + n0 + c0] = v;
        }
    } else {
        for (int i = 0; i < 4; i++)
            for (int j = 0; j < 4; j++) {
                int col = n0 + c0 + j;
                if (col < N) dst[(size_t)(b0 + i) * N + col] = acc[i][j];
            }
    }
}

// Layer-0 cell update; also emits fp16 hi/lo split of new h1 (if h1h != 0).
__global__ __launch_bounds__(256) void cell0_kernel(
    const float* __restrict__ part,
    const float* __restrict__ Wih0, const float* __restrict__ bih,
    const float* __restrict__ bhh,
    const int* __restrict__ captions, const int* __restrict__ tfmask,
    const int* __restrict__ amax,
    float* __restrict__ h1, float* __restrict__ c1,
    f16* __restrict__ h1h, f16* __restrict__ h1l, int t)
{
    int idx = blockIdx.x * 256 + threadIdx.x;
    int b = idx >> 10, i = idx & 1023;
    int tok;
    if (t == 1) tok = captions[b * TDIM];
    else tok = tfmask[t - 1] ? captions[b * TDIM + (t - 1)] : amax[b];

    float g[4];
    #pragma unroll
    for (int gi = 0; gi < 4; gi++) {
        int j = gi * HDIM + i;
        float s = bih[j] + bhh[j] + Wih0[(size_t)j * VDIM + tok];
        #pragma unroll
        for (int q = 0; q < 4; q++) s += part[(size_t)q * 262144 + b * 4096 + j];
        g[gi] = s;
    }
    float ig = sigmoidf_(g[0]), fg = sigmoidf_(g[1]);
    float gg = tanhf(g[2]),     og = sigmoidf_(g[3]);
    float cn = fg * c1[idx] + ig * gg;
    float hn = og * tanhf(cn);
    c1[idx] = cn; h1[idx] = hn;
    if (h1h) {
        f16 hh = (f16)hn;
        h1h[idx] = hh;
        h1l[idx] = (f16)((hn - (float)hh) * 2048.0f);
    }
}

// Layer-1 cell update; also emits fp16 hi/lo split of new h2.
__global__ __launch_bounds__(256) void cell1_kernel(
    const float* __restrict__ part,
    const float* __restrict__ bih, const float* __restrict__ bhh,
    float* __restrict__ h2, float* __restrict__ c2,
    f16* __restrict__ h2h, f16* __restrict__ h2l)
{
    int idx = blockIdx.x * 256 + threadIdx.x;
    int b = idx >> 10, i = idx & 1023;
    float g[4];
    #pragma unroll
    for (int gi = 0; gi < 4; gi++) {
        int j = gi * HDIM + i;
        float s = bih[j] + bhh[j];
        #pragma unroll
        for (int q = 0; q < 8; q++) s += part[(size_t)q * 262144 + b * 4096 + j];
        g[gi] = s;
    }
    float ig = sigmoidf_(g[0]), fg = sigmoidf_(g[1]);
    float gg = tanhf(g[2]),     og = sigmoidf_(g[3]);
    float cn = fg * c2[idx] + ig * gg;
    float hn = og * tanhf(cn);
    c2[idx] = cn; h2[idx] = hn;
    if (h2h) {
        f16 hh = (f16)hn;
        h2h[idx] = hh;
        h2l[idx] = (f16)((hn - (float)hh) * 2048.0f);
    }
}

// Sum logit partials + bias, write out[:, t, :], block-reduce argmax per batch.
__global__ __launch_bounds__(256) void sumarg_kernel(
    const float* __restrict__ part, const float* __restrict__ b_out,
    float* __restrict__ out, int* __restrict__ amax, int t, int pstride)
{
    int b = blockIdx.x;
    int tid = threadIdx.x;
    const float* p0 = part + (size_t)b * pstride;
    const float* p1 = part + (size_t)64 * pstride + (size_t)b * pstride;
    float* orow = out + (size_t)b * TDIM * VDIM + (size_t)t * VDIM;

    unsigned long long best = 0ull;
    for (int v = tid; v < VDIM; v += 256) {
        float s = p0[v] + p1[v] + b_out[v];
        orow[v] = s;
        unsigned u = __float_as_uint(s);
        u = (u & 0x80000000u) ? ~u : (u | 0x80000000u);
        unsigned long long e = ((unsigned long long)u << 32) | (unsigned)(~v);
        if (e > best) best = e;
    }
    #pragma unroll
    for (int off = 32; off > 0; off >>= 1) {
        unsigned long long o = __shfl_down(best, off, 64);
        if (o > best) best = o;
    }
    __shared__ unsigned long long red[4];
    if ((tid & 63) == 0) red[tid >> 6] = best;
    __syncthreads();
    if (tid == 0) {
        best = red[0];
        if (red[1] > best) best = red[1];
        if (red[2] > best) best = red[2];
        if (red[3] > best) best = red[3];
        amax[b] = (int)(~(unsigned)(best & 0xffffffffull));
    }
}

// Copy initial states (+ fp16 splits), write out[:,0,:] = one_hot.
__global__ __launch_bounds__(256) void init_kernel(
    const float* __restrict__ hidden, const float* __restrict__ cell,
    const int* __restrict__ captions,
    float* __restrict__ h1, float* __restrict__ c1,
    float* __restrict__ h2, float* __restrict__ c2,
    f16* __restrict__ h1h, f16* __restrict__ h1l,
    f16* __restrict__ h2h, f16* __restrict__ h2l,
    float* __restrict__ out)
{
    int idx = blockIdx.x * 256 + threadIdx.x;
    if (idx < BDIM * HDIM) {
        float a = hidden[idx];
        float b = hidden[BDIM * HDIM + idx];
        h1[idx] = a;
        h2[idx] = b;
        c1[idx] = cell[idx];
        c2[idx] = cell[BDIM * HDIM + idx];
        if (h1h) {
            f16 ah = (f16)a;
            h1h[idx] = ah; h1l[idx] = (f16)((a - (float)ah) * 2048.0f);
            f16 bh = (f16)b;
            h2h[idx] = bh; h2l[idx] = (f16)((b - (float)bh) * 2048.0f);
        }
    }
    if (idx < BDIM * VDIM) {
        int b = idx / VDIM, v = idx % VDIM;
        out[(size_t)b * TDIM * VDIM + v] = (v == captions[b * TDIM]) ? 1.0f : 0.0f;
    }
}

extern "C" void kernel_launch(void* const* d_in, const int* in_sizes, int n_in,
                              void* d_out, int out_size, void* d_ws, size_t ws_size,
                              hipStream_t stream)
{
    const float* hidden = (const float*)d_in[0];
    const float* cellin = (const float*)d_in[1];
    const int*   captions = (const int*)d_in[2];
    const int*   tfmask = (const int*)d_in[3];
    const float* Wih0 = (const float*)d_in[4];
    const float* Whh0 = (const float*)d_in[5];
    const float* bih0 = (const float*)d_in[6];
    const float* bhh0 = (const float*)d_in[7];
    const float* Wih1 = (const float*)d_in[8];
    const float* Whh1 = (const float*)d_in[9];
    const float* bih1 = (const float*)d_in[10];
    const float* bhh1 = (const float*)d_in[11];
    const float* Wout = (const float*)d_in[12];
    const float* bout = (const float*)d_in[13];
    float* out = (float*)d_out;

    char* wsb = (char*)d_ws;
    // fp32 state block
    float* h1 = (float*)(wsb + 0);
    float* c1 = (float*)(wsb + 262144);
    float* h2 = (float*)(wsb + 524288);
    float* c2 = (float*)(wsb + 786432);
    int*   amax = (int*)(wsb + 1048576);
    // fp16 h splits
    f16* h1h = (f16*)(wsb + 1049600);
    f16* h1l = (f16*)(wsb + 1180672);
    f16* h2h = (f16*)(wsb + 1311744);
    f16* h2l = (f16*)(wsb + 1442816);
    // partials: 8 slabs of 64x4096 f32 (gemm3 reuses as 2 slabs of 64x10048)
    float* part = (float*)(wsb + 1573888);
    // converted weights
    size_t wb = 9962496;
    const size_t WSQ = (size_t)4096 * 1024 * 2;        // 8 MB per half
    const size_t WVO = (size_t)VPAD * 1024 * 2;        // 20.6 MB per half
    f16* Whh0h = (f16*)(wsb + wb);
    f16* Whh0l = (f16*)(wsb + wb + WSQ);
    f16* Wih1h = (f16*)(wsb + wb + 2 * WSQ);
    f16* Wih1l = (f16*)(wsb + wb + 3 * WSQ);
    f16* Whh1h = (f16*)(wsb + wb + 4 * WSQ);
    f16* Whh1l = (f16*)(wsb + wb + 5 * WSQ);
    f16* Wouth = (f16*)(wsb + wb + 6 * WSQ);
    f16* Woutl = (f16*)(wsb + wb + 6 * WSQ + WVO);
    const size_t ws_needed = wb + 6 * WSQ + 2 * WVO;   // ~101.5 MB

    const bool use_mfma = (ws_size >= ws_needed);

    if (use_mfma) {
        init_kernel<<<2500, 256, 0, stream>>>(hidden, cellin, captions,
                                              h1, c1, h2, c2,
                                              h1h, h1l, h2h, h2l, out);
        // one-time weight conversion (per launch; ws is re-poisoned each call)
        int nsq = 4096 * 1024;
        convert_split<<<nsq / 256, 256, 0, stream>>>(Whh0, Whh0h, Whh0l, nsq, nsq);
        convert_split<<<nsq / 256, 256, 0, stream>>>(Wih1, Wih1h, Wih1l, nsq, nsq);
        convert_split<<<nsq / 256, 256, 0, stream>>>(Whh1, Whh1h, Whh1l, nsq, nsq);
        int nvo = VPAD * 1024;
        convert_split<<<nvo / 256, 256, 0, stream>>>(Wout, Wouth, Woutl,
                                                     VDIM * 1024, nvo);

        for (int t = 1; t < TDIM; t++) {
            gemm_mfma<<<dim3(64, 4, 1), 256, 0, stream>>>(
                h1h, h1l, Whh0h, Whh0l, h1h, h1l, Whh0h, Whh0l, part, 4096, 4);
            cell0_kernel<<<256, 256, 0, stream>>>(part, Wih0, bih0, bhh0,
                                                  captions, tfmask, amax,
                                                  h1, c1, h1h, h1l, t);
            gemm_mfma<<<dim3(64, 4, 2), 256, 0, stream>>>(
                h1h, h1l, Wih1h, Wih1l, h2h, h2l, Whh1h, Whh1l, part, 4096, 4);
            cell1_kernel<<<256, 256, 0, stream>>>(part, bih1, bhh1,
                                                  h2, c2, h2h, h2l);
            gemm_mfma<<<dim3(157, 2, 1), 256, 0, stream>>>(
                h2h, h2l, Wouth, Woutl, h2h, h2l, Wouth, Woutl, part, VPAD, 2);
            sumarg_kernel<<<64, 256, 0, stream>>>(part, bout, out, amax, t, VPAD);
        }
    } else {
        // fallback: round-0 fp32 path
        init_kernel<<<2500, 256, 0, stream>>>(hidden, cellin, captions,
                                              h1, c1, h2, c2,
                                              (f16*)0, (f16*)0, (f16*)0, (f16*)0, out);
        for (int t = 1; t < TDIM; t++) {
            gemm_ksplit<<<dim3(64, 4, 1), 256, 0, stream>>>(h1, Whh0, h1, Whh0, part, 4096, 4);
            cell0_kernel<<<256, 256, 0, stream>>>(part, Wih0, bih0, bhh0,
                                                  captions, tfmask, amax,
                                                  h1, c1, (f16*)0, (f16*)0, t);
            gemm_ksplit<<<dim3(64, 4, 2), 256, 0, stream>>>(h1, Wih1, h2, Whh1, part, 4096, 4);
            cell1_kernel<<<256, 256, 0, stream>>>(part, bih1, bhh1,
                                                  h2, c2, (f16*)0, (f16*)0);
            gemm_ksplit<<<dim3(157, 2, 1), 256, 0, stream>>>(h2, Wout, h2, Wout, part, VDIM, 2);
            sumarg_kernel<<<64, 256, 0, stream>>>(part, bout, out, amax, t, VDIM);
        }
    }
}